// Round 2
// baseline (303.553 us; speedup 1.0000x reference)
//
#include <hip/hip_runtime.h>

// EarlyRewardLoss, N=4096, T=365, C=32.
// Kernel 1: block-per-row. Coalesced float4 read of the whole logp row
// (same HBM sectors the scatter-gather touched, but streamed), select
// logp[t][y[t]] into LDS, then wave 0 does the multiplicative prefix scan
// (Pt) + both reductions. One partial per row -> d_ws.
// Kernel 2: single block reduces 4096 partials -> out[0]. No atomics.

constexpr int   T_DIM      = 365;
constexpr int   C_DIM      = 32;
constexpr int   N_DIM      = 4096;
constexpr float EPS_OVER_T = 10.0f / 365.0f;
constexpr int   F4_PER_ROW = T_DIM * C_DIM / 4;   // 2920 float4 per row
constexpr int   ITERS      = (F4_PER_ROW + 255) / 256;  // 12

__global__ __launch_bounds__(256)
void row_kernel(const float* __restrict__ logp,   // [N,T,C]
                const float* __restrict__ ps,     // [N,T]
                const int*   __restrict__ yt,     // [N,T]
                float* __restrict__ partial)      // [N]
{
    const int tid = threadIdx.x;
    const int row = blockIdx.x;

    const float4* lp4 = (const float4*)(logp + (size_t)row * (T_DIM * C_DIM));
    const float*  psr = ps + (size_t)row * T_DIM;
    const int*    ytr = yt + (size_t)row * T_DIM;

    __shared__ int   sy [T_DIM];
    __shared__ float sps[T_DIM];
    __shared__ float slp[T_DIM];

    // ---- phase 0: issue y_true / ps row loads (coalesced) ----
    int   y0 = 0, y1 = 0;
    float p0 = 0.f, p1 = 0.f;
    const int  t1   = tid + 256;
    const bool has0 = (tid < T_DIM);
    const bool has1 = (t1  < T_DIM);
    if (has0) { y0 = ytr[tid]; p0 = psr[tid]; }
    if (has1) { y1 = ytr[t1];  p1 = psr[t1]; }

    // ---- phase 1: issue ALL logp float4 loads before any wait (MLP) ----
    float4 v[ITERS];
    #pragma unroll
    for (int j = 0; j < ITERS; ++j) {
        const int f = tid + j * 256;
        if (f < F4_PER_ROW) v[j] = lp4[f];
    }

    if (has0) { sy[tid] = y0; sps[tid] = p0; }
    if (has1) { sy[t1]  = y1; sps[t1]  = p1; }
    __syncthreads();

    // select logp[t][y[t]] -> slp[t]; each float4 covers (t = f>>3, c = (f&7)*4..+3)
    #pragma unroll
    for (int j = 0; j < ITERS; ++j) {
        const int f = tid + j * 256;
        if (f < F4_PER_ROW) {
            const int t  = f >> 3;
            const int c0 = (f & 7) << 2;
            const unsigned d = (unsigned)(sy[t] - c0);
            if (d < 4u) slp[t] = ((const float*)&v[j])[d];
        }
    }
    __syncthreads();

    // ---- phase 2: wave 0 does the scan + reductions ----
    if (tid < 64) {
        const int lane = tid;
        float carry = 1.0f, cl = 0.0f, er = 0.0f;

        #pragma unroll
        for (int k = 0; k < 6; ++k) {
            const int t = k * 64 + lane;
            float d;
            if (t < T_DIM - 1)       d = sps[t + 1];
            else if (t == T_DIM - 1) d = 1.0f;
            else                     d = 0.0f;    // pad: m=1, no scan effect

            float s = 1.0f - d;
            #pragma unroll
            for (int off = 1; off < 64; off <<= 1) {
                const float o = __shfl_up(s, off);
                if (lane >= off) s *= o;
            }
            float e = __shfl_up(s, 1);
            if (lane == 0) e = 1.0f;

            const float pt = d * carry * e + EPS_OVER_T;
            carry *= __shfl(s, 63);

            if (t < T_DIM) {
                const float lp = slp[t];
                cl += lp * pt;
                er += pt * __expf(lp) * (1.0f - (float)t * (1.0f / T_DIM));
            }
        }

        #pragma unroll
        for (int off = 32; off > 0; off >>= 1) {
            cl += __shfl_xor(cl, off);
            er += __shfl_xor(er, off);
        }
        if (lane == 0)
            partial[row] = (-0.5f * (cl + er)) * (1.0f / (float)N_DIM);
    }
}

__global__ __launch_bounds__(256)
void reduce_kernel(const float* __restrict__ partial, float* __restrict__ out)
{
    const int tid = threadIdx.x;
    float s = 0.0f;
    #pragma unroll
    for (int j = 0; j < N_DIM / 256; ++j) s += partial[tid + j * 256];

    #pragma unroll
    for (int off = 32; off > 0; off >>= 1) s += __shfl_xor(s, off);

    __shared__ float w[4];
    if ((tid & 63) == 0) w[tid >> 6] = s;
    __syncthreads();
    if (tid == 0) out[0] = w[0] + w[1] + w[2] + w[3];
}

extern "C" void kernel_launch(void* const* d_in, const int* in_sizes, int n_in,
                              void* d_out, int out_size, void* d_ws, size_t ws_size,
                              hipStream_t stream) {
    const float* logp = (const float*)d_in[0];
    const float* ps   = (const float*)d_in[1];
    const int*   yt   = (const int*)d_in[2];
    float* out     = (float*)d_out;
    float* partial = (float*)d_ws;   // 4096 floats = 16 KB

    row_kernel<<<N_DIM, 256, 0, stream>>>(logp, ps, yt, partial);
    reduce_kernel<<<1, 256, 0, stream>>>(partial, out);
}

// Round 3
// 271.889 us; speedup vs baseline: 1.1165x; 1.1165x over previous
//
#include <hip/hip_runtime.h>

// EarlyRewardLoss, N=4096, T=365, C=32.
// Kernel 1: block-per-row. yt/ps rows are coalesced loads; logp is a
// per-(n,t) gather of ONE aligned float4 (16B) containing logp[t][y[t]]
// -- touches one 64B sector per (n,t) instead of streaming the full 128B
// class-row. Element select via branchless ternary (cndmask), never
// dynamic local-array indexing (R2's scratch-spill bug: VGPR=28 +
// WRITE_SIZE=187MB proved v[] lived in scratch).
// Wave 0 then does the multiplicative prefix scan (Pt) + reductions.
// Kernel 2: single block reduces 4096 partials. No atomics.

constexpr int   T_DIM      = 365;
constexpr int   C_DIM      = 32;
constexpr int   N_DIM      = 4096;
constexpr float EPS_OVER_T = 10.0f / 365.0f;

__device__ __forceinline__ float sel4(float4 v, int d) {
    // branchless: 3 v_cndmask, no memory
    float r = (d == 1) ? v.y : v.x;
    r       = (d == 2) ? v.z : r;
    r       = (d == 3) ? v.w : r;
    return r;
}

__global__ __launch_bounds__(256)
void row_kernel(const float* __restrict__ logp,   // [N,T,C]
                const float* __restrict__ ps,     // [N,T]
                const int*   __restrict__ yt,     // [N,T]
                float* __restrict__ partial)      // [N]
{
    const int tid = threadIdx.x;
    const int row = blockIdx.x;

    const float* lpr = logp + (size_t)row * (T_DIM * C_DIM);
    const float* psr = ps   + (size_t)row * T_DIM;
    const int*   ytr = yt   + (size_t)row * T_DIM;

    __shared__ float sps[T_DIM];
    __shared__ float slp[T_DIM];

    // ---- coalesced yt/ps loads (both issued before any use) ----
    const int t1 = tid + 256;
    int   y0 = 0, y1 = 0;
    float p0 = 0.f, p1 = 0.f;
    const bool has0 = (tid < T_DIM);
    const bool has1 = (t1  < T_DIM);
    if (has0) { y0 = ytr[tid]; p0 = psr[tid]; }
    if (has1) { y1 = ytr[t1];  p1 = psr[t1]; }

    // ---- gather the aligned float4 containing logp[t][y] ----
    float4 v0, v1;
    if (has0) v0 = *(const float4*)(lpr + tid * C_DIM + (y0 & ~3));
    if (has1) v1 = *(const float4*)(lpr + t1  * C_DIM + (y1 & ~3));

    if (has0) { sps[tid] = p0; slp[tid] = sel4(v0, y0 & 3); }
    if (has1) { sps[t1]  = p1; slp[t1]  = sel4(v1, y1 & 3); }
    __syncthreads();

    // ---- wave 0: multiplicative prefix scan + reductions ----
    if (tid < 64) {
        const int lane = tid;
        float carry = 1.0f, cl = 0.0f, er = 0.0f;

        #pragma unroll
        for (int k = 0; k < 6; ++k) {
            const int t = k * 64 + lane;
            float d;
            if (t < T_DIM - 1)       d = sps[t + 1];
            else if (t == T_DIM - 1) d = 1.0f;
            else                     d = 0.0f;    // pad: m=1, no scan effect

            float s = 1.0f - d;
            #pragma unroll
            for (int off = 1; off < 64; off <<= 1) {
                const float o = __shfl_up(s, off);
                if (lane >= off) s *= o;
            }
            float e = __shfl_up(s, 1);
            if (lane == 0) e = 1.0f;

            const float pt = d * carry * e + EPS_OVER_T;
            carry *= __shfl(s, 63);

            if (t < T_DIM) {
                const float lp = slp[t];
                cl += lp * pt;
                er += pt * __expf(lp) * (1.0f - (float)t * (1.0f / T_DIM));
            }
        }

        #pragma unroll
        for (int off = 32; off > 0; off >>= 1) {
            cl += __shfl_xor(cl, off);
            er += __shfl_xor(er, off);
        }
        if (lane == 0)
            partial[row] = (-0.5f * (cl + er)) * (1.0f / (float)N_DIM);
    }
}

__global__ __launch_bounds__(256)
void reduce_kernel(const float* __restrict__ partial, float* __restrict__ out)
{
    const int tid = threadIdx.x;
    float s = 0.0f;
    #pragma unroll
    for (int j = 0; j < N_DIM / 256; ++j) s += partial[tid + j * 256];

    #pragma unroll
    for (int off = 32; off > 0; off >>= 1) s += __shfl_xor(s, off);

    __shared__ float w[4];
    if ((tid & 63) == 0) w[tid >> 6] = s;
    __syncthreads();
    if (tid == 0) out[0] = w[0] + w[1] + w[2] + w[3];
}

extern "C" void kernel_launch(void* const* d_in, const int* in_sizes, int n_in,
                              void* d_out, int out_size, void* d_ws, size_t ws_size,
                              hipStream_t stream) {
    const float* logp = (const float*)d_in[0];
    const float* ps   = (const float*)d_in[1];
    const int*   yt   = (const int*)d_in[2];
    float* out     = (float*)d_out;
    float* partial = (float*)d_ws;   // 4096 floats = 16 KB

    row_kernel<<<N_DIM, 256, 0, stream>>>(logp, ps, yt, partial);
    reduce_kernel<<<1, 256, 0, stream>>>(partial, out);
}

// Round 4
// 270.438 us; speedup vs baseline: 1.1225x; 1.0054x over previous
//
#include <hip/hip_runtime.h>

// EarlyRewardLoss, N=4096, T=365, C=32.
// R4 = R2's coalesced-streaming structure + R3's branchless select.
// Theory: the per-(n,t) gather fetches a full 128B L2 line anyway, so the
// whole logp tensor (191 MB) comes over HBM either way; streaming it
// coalesced runs at ~6 TB/s instead of gather's ~2.5 TB/s.
// R2's failure was scratch spill from dynamic indexing of the float4
// buffer (VGPR=28, WRITE_SIZE=187MB); sel4's cndmask chain keeps all 12
// in-flight float4 in VGPRs.
// Kernel 1: block-per-row. Stage sy/sps in LDS; stream the row's 2920
// float4 with 12 independent loads/thread; select logp[t][y[t]] -> slp.
// Wave 0 then does the multiplicative prefix scan (Pt) + reductions.
// Kernel 2: single block reduces 4096 partials. No atomics.

constexpr int   T_DIM      = 365;
constexpr int   C_DIM      = 32;
constexpr int   N_DIM      = 4096;
constexpr float EPS_OVER_T = 10.0f / 365.0f;
constexpr int   F4_PER_ROW = T_DIM * C_DIM / 4;        // 2920
constexpr int   ITERS      = (F4_PER_ROW + 255) / 256; // 12

__device__ __forceinline__ float sel4(float4 v, unsigned d) {
    // branchless: 3 v_cndmask, no memory, no address-of
    float r = (d == 1u) ? v.y : v.x;
    r       = (d == 2u) ? v.z : r;
    r       = (d == 3u) ? v.w : r;
    return r;
}

__global__ __launch_bounds__(256)
void row_kernel(const float* __restrict__ logp,   // [N,T,C]
                const float* __restrict__ ps,     // [N,T]
                const int*   __restrict__ yt,     // [N,T]
                float* __restrict__ partial)      // [N]
{
    const int tid = threadIdx.x;
    const int row = blockIdx.x;

    const float4* lp4 = (const float4*)(logp + (size_t)row * (T_DIM * C_DIM));
    const float*  psr = ps + (size_t)row * T_DIM;
    const int*    ytr = yt + (size_t)row * T_DIM;

    __shared__ int   sy [T_DIM];
    __shared__ float sps[T_DIM];
    __shared__ float slp[T_DIM];

    // ---- coalesced yt/ps row loads -> LDS ----
    const int  t1   = tid + 256;
    const bool has0 = (tid < T_DIM);
    const bool has1 = (t1  < T_DIM);
    int   y0 = 0, y1 = 0;
    float p0 = 0.f, p1 = 0.f;
    if (has0) { y0 = ytr[tid]; p0 = psr[tid]; }
    if (has1) { y1 = ytr[t1];  p1 = psr[t1]; }
    if (has0) { sy[tid] = y0; sps[tid] = p0; }
    if (has1) { sy[t1]  = y1; sps[t1]  = p1; }
    __syncthreads();

    // ---- stream the logp row; 12 independent float4 loads per thread ----
    // Each float4 covers (t = f>>3, classes c0..c0+3, c0 = (f&7)*4).
    {
        float4 v0, v1, v2, v3, v4, v5, v6, v7, v8, v9, v10, v11;
        const int f0 = tid;
        v0  = lp4[f0          ];
        v1  = lp4[f0 +  1*256 ];
        v2  = lp4[f0 +  2*256 ];
        v3  = lp4[f0 +  3*256 ];
        v4  = lp4[f0 +  4*256 ];
        v5  = lp4[f0 +  5*256 ];
        v6  = lp4[f0 +  6*256 ];
        v7  = lp4[f0 +  7*256 ];
        v8  = lp4[f0 +  8*256 ];
        v9  = lp4[f0 +  9*256 ];
        v10 = lp4[f0 + 10*256 ];
        if (f0 + 11*256 < F4_PER_ROW) v11 = lp4[f0 + 11*256];

        #define SELSTORE(vv, jj)                                         \
        do {                                                             \
            const int f = tid + (jj) * 256;                              \
            if (f < F4_PER_ROW) {                                        \
                const int t  = f >> 3;                                   \
                const int c0 = (f & 7) << 2;                             \
                const unsigned d = (unsigned)(sy[t] - c0);               \
                if (d < 4u) slp[t] = sel4(vv, d);                        \
            }                                                            \
        } while (0)

        SELSTORE(v0, 0);  SELSTORE(v1, 1);  SELSTORE(v2, 2);
        SELSTORE(v3, 3);  SELSTORE(v4, 4);  SELSTORE(v5, 5);
        SELSTORE(v6, 6);  SELSTORE(v7, 7);  SELSTORE(v8, 8);
        SELSTORE(v9, 9);  SELSTORE(v10,10); SELSTORE(v11,11);
        #undef SELSTORE
    }
    __syncthreads();

    // ---- wave 0: multiplicative prefix scan + reductions ----
    if (tid < 64) {
        const int lane = tid;
        float carry = 1.0f, cl = 0.0f, er = 0.0f;

        #pragma unroll
        for (int k = 0; k < 6; ++k) {
            const int t = k * 64 + lane;
            float d;
            if (t < T_DIM - 1)       d = sps[t + 1];
            else if (t == T_DIM - 1) d = 1.0f;
            else                     d = 0.0f;    // pad: m=1, no scan effect

            float s = 1.0f - d;
            #pragma unroll
            for (int off = 1; off < 64; off <<= 1) {
                const float o = __shfl_up(s, off);
                if (lane >= off) s *= o;
            }
            float e = __shfl_up(s, 1);
            if (lane == 0) e = 1.0f;

            const float pt = d * carry * e + EPS_OVER_T;
            carry *= __shfl(s, 63);

            if (t < T_DIM) {
                const float lp = slp[t];
                cl += lp * pt;
                er += pt * __expf(lp) * (1.0f - (float)t * (1.0f / T_DIM));
            }
        }

        #pragma unroll
        for (int off = 32; off > 0; off >>= 1) {
            cl += __shfl_xor(cl, off);
            er += __shfl_xor(er, off);
        }
        if (lane == 0)
            partial[row] = (-0.5f * (cl + er)) * (1.0f / (float)N_DIM);
    }
}

__global__ __launch_bounds__(256)
void reduce_kernel(const float* __restrict__ partial, float* __restrict__ out)
{
    const int tid = threadIdx.x;
    float s = 0.0f;
    #pragma unroll
    for (int j = 0; j < N_DIM / 256; ++j) s += partial[tid + j * 256];

    #pragma unroll
    for (int off = 32; off > 0; off >>= 1) s += __shfl_xor(s, off);

    __shared__ float w[4];
    if ((tid & 63) == 0) w[tid >> 6] = s;
    __syncthreads();
    if (tid == 0) out[0] = w[0] + w[1] + w[2] + w[3];
}

extern "C" void kernel_launch(void* const* d_in, const int* in_sizes, int n_in,
                              void* d_out, int out_size, void* d_ws, size_t ws_size,
                              hipStream_t stream) {
    const float* logp = (const float*)d_in[0];
    const float* ps   = (const float*)d_in[1];
    const int*   yt   = (const int*)d_in[2];
    float* out     = (float*)d_out;
    float* partial = (float*)d_ws;   // 4096 floats = 16 KB

    row_kernel<<<N_DIM, 256, 0, stream>>>(logp, ps, yt, partial);
    reduce_kernel<<<1, 256, 0, stream>>>(partial, out);
}